// Round 6
// baseline (48.767 us; speedup 1.0000x reference)
//
#include <hip/hip_runtime.h>

typedef unsigned short ushort_t;
typedef __attribute__((ext_vector_type(8))) short short8;
typedef __attribute__((ext_vector_type(4))) float f32x4;

__device__ __forceinline__ ushort_t f2b(float x) {
    unsigned int u = __builtin_bit_cast(unsigned int, x);
    u += 0x7FFFu + ((u >> 16) & 1u);   // round-to-nearest-even
    return (ushort_t)(u >> 16);
}
__device__ __forceinline__ float b2f(ushort_t b) {
    unsigned int u = ((unsigned int)b) << 16;
    return __builtin_bit_cast(float, u);
}

// pack 8 consecutive floats into bf16 hi + bf16 residual(lo)
__device__ __forceinline__ void pack_pair(const float* __restrict__ p,
                                          short8& hi, short8& lo) {
    float4 f0 = *reinterpret_cast<const float4*>(p);
    float4 f1 = *reinterpret_cast<const float4*>(p + 4);
    float f[8] = {f0.x, f0.y, f0.z, f0.w, f1.x, f1.y, f1.z, f1.w};
#pragma unroll
    for (int e = 0; e < 8; ++e) {
        ushort_t hb = f2b(f[e]);
        hi[e] = (short)hb;
        float r = f[e] - b2f(hb);
        lo[e] = (short)f2b(r);
    }
}

// ---- precompute (exact via split-bf16 MFMA) + int8 row quantization ----
// hu_row = W1[:, :64] @ u + b1 ; hi_row = W1[:, 64:] @ i
// stored as biased uint8 mantissas (32 B/row) + fp32 per-row scale
__global__ __launch_bounds__(256) void precompute_q8(
    const float* __restrict__ ue, const float* __restrict__ ie,
    const float* __restrict__ W1, const float* __restrict__ b1,
    unsigned char* __restrict__ um, unsigned char* __restrict__ im,
    float* __restrict__ usc, float* __restrict__ isc,
    int nu, int ni, int ntu, int ntot)
{
    const int l  = threadIdx.x & 63;
    const int lj = l & 15;   // table row within tile
    const int lg = l >> 4;   // k-group; D rows lg*4..lg*4+3

    int wid = blockIdx.x * (blockDim.x >> 6) + (threadIdx.x >> 6);
    if (wid >= ntot) return;
    const bool isU = wid < ntu;
    const float* tab = isU ? ue : ie;
    unsigned char* mant = isU ? um : im;
    float* sc = isU ? usc : isc;
    const int nrows = isU ? nu : ni;
    const int tb   = (isU ? wid : wid - ntu) * 16;
    const int toff = isU ? 0 : 64;

    short8 ahi[2][2], alo[2][2];
#pragma unroll
    for (int ks = 0; ks < 2; ++ks)
#pragma unroll
        for (int g = 0; g < 2; ++g)
            pack_pair(W1 + (g * 16 + lj) * 128 + toff + ks * 32 + lg * 8,
                      ahi[ks][g], alo[ks][g]);

    int r = tb + lj; if (r >= nrows) r = nrows - 1;
    const float* rp = tab + (long)r * 64;
    short8 bhi0, blo0, bhi1, blo1;
    pack_pair(rp + lg * 8,      bhi0, blo0);
    pack_pair(rp + 32 + lg * 8, bhi1, blo1);

    f32x4 acc[2];
#pragma unroll
    for (int g = 0; g < 2; ++g)
#pragma unroll
        for (int q = 0; q < 4; ++q)
            acc[g][q] = isU ? b1[g * 16 + lg * 4 + q] : 0.f;

#pragma unroll
    for (int g = 0; g < 2; ++g) {
        acc[g] = __builtin_amdgcn_mfma_f32_16x16x32_bf16(ahi[0][g], bhi0, acc[g], 0, 0, 0);
        acc[g] = __builtin_amdgcn_mfma_f32_16x16x32_bf16(ahi[0][g], blo0, acc[g], 0, 0, 0);
        acc[g] = __builtin_amdgcn_mfma_f32_16x16x32_bf16(alo[0][g], bhi0, acc[g], 0, 0, 0);
        acc[g] = __builtin_amdgcn_mfma_f32_16x16x32_bf16(ahi[1][g], bhi1, acc[g], 0, 0, 0);
        acc[g] = __builtin_amdgcn_mfma_f32_16x16x32_bf16(ahi[1][g], blo1, acc[g], 0, 0, 0);
        acc[g] = __builtin_amdgcn_mfma_f32_16x16x32_bf16(alo[1][g], bhi1, acc[g], 0, 0, 0);
    }

    // row max over the 32 values (4 lanes x 8 regs per row)
    float m = 0.f;
#pragma unroll
    for (int g = 0; g < 2; ++g)
#pragma unroll
        for (int q = 0; q < 4; ++q)
            m = fmaxf(m, fabsf(acc[g][q]));
    m = fmaxf(m, __shfl_xor(m, 16));
    m = fmaxf(m, __shfl_xor(m, 32));
    float inv = m > 0.f ? 127.f / m : 0.f;

    if (tb + lj < nrows) {
#pragma unroll
        for (int g = 0; g < 2; ++g) {
            unsigned int w = 0;
#pragma unroll
            for (int q = 0; q < 4; ++q) {
                float qf = __builtin_rintf(acc[g][q] * inv);
                qf = fminf(fmaxf(qf, -127.f), 127.f);
                int qi = (int)qf + 128;               // biased uint8, 1..255
                w |= ((unsigned int)qi & 0xFFu) << (8 * q);
            }
            *reinterpret_cast<unsigned int*>(mant + (long)r * 32 + g * 16 + lg * 4) = w;
        }
        if (lg == 0) sc[r] = m * (1.f / 127.f);
    }
}

// ---- main: one-shot waves (r3 structure), int8 gather (32B/row) + scales ----
__global__ __launch_bounds__(256) void edge_final_q8(
    const unsigned char* __restrict__ um, const unsigned char* __restrict__ im,
    const float* __restrict__ usc, const float* __restrict__ isc,
    const float* __restrict__ w2, const float* __restrict__ b2v,
    const int* __restrict__ idx, float* __restrict__ out,
    long E, long ngroups)
{
    const int l = threadIdx.x & 63;
    const int c = l & 3;    // chunk: h elements c*8 .. c*8+7
    const int g = l >> 2;   // edge-within-16

    long wid = (long)blockIdx.x * (blockDim.x >> 6) + (threadIdx.x >> 6);
    if (wid >= ngroups) return;

    float w2v[8];
#pragma unroll
    for (int q = 0; q < 8; ++q) w2v[q] = w2[c * 8 + q];
    const float bb2 = b2v[0];

    long e0 = wid * 64;
    long el = e0 + l; if (el >= E) el = E - 1;
    int uidx = idx[el];        // coalesced: lane l <-> edge
    int iidx = idx[E + el];

    uint2 mu[4], mi[4];
    float su[4], si[4];
#pragma unroll
    for (int s = 0; s < 4; ++s) {
        int u  = __shfl(uidx, s * 16 + g);
        int it = __shfl(iidx, s * 16 + g);
        mu[s] = *reinterpret_cast<const uint2*>(um + (long)u  * 32 + c * 8);
        mi[s] = *reinterpret_cast<const uint2*>(im + (long)it * 32 + c * 8);
        su[s] = usc[u];
        si[s] = isc[it];
    }

    float pt[4];
#pragma unroll
    for (int s = 0; s < 4; ++s) {
        const float a = su[s], b = si[s];
        const float off = -128.f * (a + b);
        float p = 0.f;
        unsigned int wu = mu[s].x, wi = mi[s].x;
#pragma unroll
        for (int q = 0; q < 4; ++q) {
            float fu = (float)((wu >> (8 * q)) & 0xFFu);   // v_cvt_f32_ubyteN
            float fi = (float)((wi >> (8 * q)) & 0xFFu);
            float h = fmaf(b, fi, fmaf(a, fu, off));
            h = fmaxf(h, 0.2f * h);                        // LeakyReLU(0.2)
            p = fmaf(h, w2v[q], p);
        }
        wu = mu[s].y; wi = mi[s].y;
#pragma unroll
        for (int q = 0; q < 4; ++q) {
            float fu = (float)((wu >> (8 * q)) & 0xFFu);
            float fi = (float)((wi >> (8 * q)) & 0xFFu);
            float h = fmaf(b, fi, fmaf(a, fu, off));
            h = fmaxf(h, 0.2f * h);
            p = fmaf(h, w2v[4 + q], p);
        }
        p += __shfl_xor(p, 1);   // reduce over the 4 chunk-lanes
        p += __shfl_xor(p, 2);
        pt[s] = p;
    }

    // lane l wants edge e0+l = subround l>>4, position l&15 (logit at lane (l&15)*4)
    int src = (l & 15) * 4;
    float v0 = __shfl(pt[0], src);
    float v1 = __shfl(pt[1], src);
    float v2 = __shfl(pt[2], src);
    float v3 = __shfl(pt[3], src);
    int sr = l >> 4;
    float pv = sr == 0 ? v0 : sr == 1 ? v1 : sr == 2 ? v2 : v3;

    float x = pv + bb2;
    float z = __builtin_amdgcn_exp2f(-1.442695040888963f * x);
    float sig = __builtin_amdgcn_rcpf(1.f + z);
    long eo = e0 + l;
    if (eo < E) out[eo] = sig;   // coalesced 256-B store
}

// ---- fallback (ws too small): fp32 VALU, thread-per-edge, W1 in LDS ----
__global__ __launch_bounds__(256) void edge_mlp_fp32(
    const float* __restrict__ ue, const float* __restrict__ ie,
    const float* __restrict__ W1, const float* __restrict__ b1,
    const float* __restrict__ w2, const float* __restrict__ b2v,
    const int* __restrict__ idx, float* __restrict__ out, long E)
{
    __shared__ float w1s[128][32];
    for (int t = threadIdx.x; t < 4096; t += blockDim.x) {
        int k = t >> 5, j = t & 31;
        w1s[k][j] = W1[j * 128 + k];
    }
    __syncthreads();
    long e = (long)blockIdx.x * blockDim.x + threadIdx.x;
    if (e >= E) return;
    int u = idx[e], it = idx[E + e];
    const float* ur = ue + (long)u * 64;
    const float* ir = ie + (long)it * 64;
    float acc[32];
#pragma unroll
    for (int j = 0; j < 32; ++j) acc[j] = b1[j];
    for (int k = 0; k < 64; k += 4) {
        float4 f = *reinterpret_cast<const float4*>(ur + k);
        float fv[4] = {f.x, f.y, f.z, f.w};
#pragma unroll
        for (int q = 0; q < 4; ++q)
#pragma unroll
            for (int j = 0; j < 32; ++j) acc[j] += w1s[k + q][j] * fv[q];
    }
    for (int k = 0; k < 64; k += 4) {
        float4 f = *reinterpret_cast<const float4*>(ir + k);
        float fv[4] = {f.x, f.y, f.z, f.w};
#pragma unroll
        for (int q = 0; q < 4; ++q)
#pragma unroll
            for (int j = 0; j < 32; ++j) acc[j] += w1s[64 + k + q][j] * fv[q];
    }
    float lgt = b2v[0];
#pragma unroll
    for (int j = 0; j < 32; ++j) {
        float h = acc[j]; h = h >= 0.f ? h : 0.2f * h;
        lgt += h * w2[j];
    }
    out[e] = 1.0f / (1.0f + expf(-lgt));
}

extern "C" void kernel_launch(void* const* d_in, const int* in_sizes, int n_in,
                              void* d_out, int out_size, void* d_ws, size_t ws_size,
                              hipStream_t stream) {
    const float* ue  = (const float*)d_in[0];
    const float* ie  = (const float*)d_in[1];
    const float* W1  = (const float*)d_in[2];
    const float* b1  = (const float*)d_in[3];
    const float* w2  = (const float*)d_in[4];
    const float* b2v = (const float*)d_in[5];
    const int*   idx = (const int*)d_in[6];
    float* out = (float*)d_out;

    long nu = in_sizes[0] / 64;
    long ni = in_sizes[1] / 64;
    long E  = in_sizes[6] / 2;

    size_t need = (size_t)(nu + ni) * 32 + (size_t)(nu + ni) * 4;
    if (ws_size >= need) {
        unsigned char* um = (unsigned char*)d_ws;
        unsigned char* im = um + (size_t)nu * 32;
        float* usc = (float*)(im + (size_t)ni * 32);
        float* isc = usc + nu;

        int ntu = (int)((nu + 15) / 16);
        int nti = (int)((ni + 15) / 16);
        int ntot = ntu + nti;
        int pblocks = (ntot + 3) / 4;
        precompute_q8<<<pblocks, 256, 0, stream>>>(ue, ie, W1, b1, um, im, usc, isc,
                                                   (int)nu, (int)ni, ntu, ntot);

        long ngroups = (E + 63) / 64;
        int mblocks = (int)((ngroups + 3) / 4);
        edge_final_q8<<<mblocks, 256, 0, stream>>>(um, im, usc, isc, w2, b2v,
                                                   idx, out, E, ngroups);
    } else {
        edge_mlp_fp32<<<(int)((E + 255) / 256), 256, 0, stream>>>(
            ue, ie, W1, b1, w2, b2v, idx, out, E);
    }
}

// Round 7
// 44.804 us; speedup vs baseline: 1.0885x; 1.0885x over previous
//
#include <hip/hip_runtime.h>

typedef unsigned short ushort_t;
typedef __attribute__((ext_vector_type(8))) short short8;
typedef __attribute__((ext_vector_type(4))) float f32x4;
typedef __attribute__((ext_vector_type(2))) _Float16 h2v;
typedef __attribute__((ext_vector_type(4))) _Float16 h4v;

__device__ __forceinline__ ushort_t f2b(float x) {
    unsigned int u = __builtin_bit_cast(unsigned int, x);
    u += 0x7FFFu + ((u >> 16) & 1u);   // round-to-nearest-even
    return (ushort_t)(u >> 16);
}

__device__ __forceinline__ short8 pack8(const float* __restrict__ p) {
    float4 f0 = *reinterpret_cast<const float4*>(p);
    float4 f1 = *reinterpret_cast<const float4*>(p + 4);
    short8 v;
    v[0] = (short)f2b(f0.x); v[1] = (short)f2b(f0.y);
    v[2] = (short)f2b(f0.z); v[3] = (short)f2b(f0.w);
    v[4] = (short)f2b(f1.x); v[5] = (short)f2b(f1.y);
    v[6] = (short)f2b(f1.z); v[7] = (short)f2b(f1.w);
    return v;
}

// ---- precompute: hu[r][32] = W1[:, :64] @ ue[r] + b1 ; hi[r][32] = W1[:, 64:] @ ie[r]
// (identical to the round-3 passing version; NO nontemporal here)
__global__ __launch_bounds__(256) void precompute_h(
    const float* __restrict__ ue, const float* __restrict__ ie,
    const float* __restrict__ W1, const float* __restrict__ b1,
    _Float16* __restrict__ hu, _Float16* __restrict__ hi,
    int nu, int ni, int ntu, int ntot)
{
    const int l  = threadIdx.x & 63;
    const int lj = l & 15;   // table row within tile (B col / D col)
    const int lg = l >> 4;   // k-group; D rows lg*4..lg*4+3

    int wid = blockIdx.x * (blockDim.x >> 6) + (threadIdx.x >> 6);
    if (wid >= ntot) return;
    const bool isU = wid < ntu;
    const float* tab = isU ? ue : ie;
    _Float16* ht = isU ? hu : hi;
    const int nrows = isU ? nu : ni;
    const int tb   = (isU ? wid : wid - ntu) * 16;
    const int toff = isU ? 0 : 64;

    short8 afrag[2][2];
#pragma unroll
    for (int ks = 0; ks < 2; ++ks)
#pragma unroll
        for (int g = 0; g < 2; ++g)
            afrag[ks][g] = pack8(W1 + (g * 16 + lj) * 128 + toff + ks * 32 + lg * 8);

    int r = tb + lj; if (r >= nrows) r = nrows - 1;
    const float* rp = tab + (long)r * 64;
    short8 bfrag0 = pack8(rp + lg * 8);
    short8 bfrag1 = pack8(rp + 32 + lg * 8);

    f32x4 acc[2];
#pragma unroll
    for (int g = 0; g < 2; ++g)
#pragma unroll
        for (int q = 0; q < 4; ++q)
            acc[g][q] = isU ? b1[g * 16 + lg * 4 + q] : 0.f;

    acc[0] = __builtin_amdgcn_mfma_f32_16x16x32_bf16(afrag[0][0], bfrag0, acc[0], 0, 0, 0);
    acc[1] = __builtin_amdgcn_mfma_f32_16x16x32_bf16(afrag[0][1], bfrag0, acc[1], 0, 0, 0);
    acc[0] = __builtin_amdgcn_mfma_f32_16x16x32_bf16(afrag[1][0], bfrag1, acc[0], 0, 0, 0);
    acc[1] = __builtin_amdgcn_mfma_f32_16x16x32_bf16(afrag[1][1], bfrag1, acc[1], 0, 0, 0);

    if (tb + lj < nrows) {
#pragma unroll
        for (int g = 0; g < 2; ++g) {
            h4v v;
#pragma unroll
            for (int q = 0; q < 4; ++q) v[q] = (_Float16)acc[g][q];
            *reinterpret_cast<h4v*>(ht + (long)r * 32 + g * 16 + lg * 4) = v;
        }
    }
}

#if __has_builtin(__builtin_amdgcn_fdot2)
__device__ __forceinline__ float fdot2(h2v a, h2v b, float c) {
    return __builtin_amdgcn_fdot2(a, b, c, false);
}
#else
__device__ __forceinline__ float fdot2(h2v a, h2v b, float c) {
    return c + (float)a[0] * (float)b[0] + (float)a[1] * (float)b[1];
}
#endif

// ---- main: round-3 body verbatim, ONE change: nontemporal idx loads + out store
// so the 19 MB of streaming traffic stops evicting the 6.4 MB h-tables from L2.
__global__ __launch_bounds__(256) void edge_final(
    const _Float16* __restrict__ hu, const _Float16* __restrict__ hi,
    const float* __restrict__ w2, const float* __restrict__ b2v,
    const int* __restrict__ idx, float* __restrict__ out,
    long E, long ngroups)
{
    const int l = threadIdx.x & 63;
    const int c = l & 3;    // chunk: h elements c*8 .. c*8+7
    const int g = l >> 2;   // edge-within-16

    long wid = (long)blockIdx.x * (blockDim.x >> 6) + (threadIdx.x >> 6);
    if (wid >= ngroups) return;

    h2v w2h[4];
#pragma unroll
    for (int k = 0; k < 4; ++k) {
        w2h[k][0] = (_Float16)w2[c * 8 + 2 * k];
        w2h[k][1] = (_Float16)w2[c * 8 + 2 * k + 1];
    }
    const float bb2 = b2v[0];
    const _Float16 sl = (_Float16)0.2f;
    const h2v slope = {sl, sl};

    long e0 = wid * 64;
    long el = e0 + l; if (el >= E) el = E - 1;
    int uidx = __builtin_nontemporal_load(idx + el);       // NT: read-once stream
    int iidx = __builtin_nontemporal_load(idx + E + el);   // NT

    uint4 hur[4], hir[4];
#pragma unroll
    for (int s = 0; s < 4; ++s) {
        int u  = __shfl(uidx, s * 16 + g);
        int it = __shfl(iidx, s * 16 + g);
        hur[s] = *reinterpret_cast<const uint4*>(hu + (long)u  * 32 + c * 8);   // temporal (hot)
        hir[s] = *reinterpret_cast<const uint4*>(hi + (long)it * 32 + c * 8);
    }

    float pt[4];
#pragma unroll
    for (int s = 0; s < 4; ++s) {
        const unsigned int* au = reinterpret_cast<const unsigned int*>(&hur[s]);
        const unsigned int* ai = reinterpret_cast<const unsigned int*>(&hir[s]);
        float p = 0.f;
#pragma unroll
        for (int k = 0; k < 4; ++k) {
            h2v a = __builtin_bit_cast(h2v, au[k]);
            h2v b = __builtin_bit_cast(h2v, ai[k]);
            h2v h = a + b;
            h = __builtin_elementwise_max(h, h * slope);   // LeakyReLU(0.2)
            p = fdot2(h, w2h[k], p);
        }
        p += __shfl_xor(p, 1);   // reduce over the 4 chunk-lanes
        p += __shfl_xor(p, 2);
        pt[s] = p;
    }

    // lane l wants edge e0+l = subround l>>4, position l&15 (logit at lane (l&15)*4)
    int src = (l & 15) * 4;
    float v0 = __shfl(pt[0], src);
    float v1 = __shfl(pt[1], src);
    float v2 = __shfl(pt[2], src);
    float v3 = __shfl(pt[3], src);
    int sr = l >> 4;
    float pv = sr == 0 ? v0 : sr == 1 ? v1 : sr == 2 ? v2 : v3;

    float x = pv + bb2;
    float z = __builtin_amdgcn_exp2f(-1.442695040888963f * x);
    float sig = __builtin_amdgcn_rcpf(1.f + z);
    long eo = e0 + l;
    if (eo < E) __builtin_nontemporal_store(sig, out + eo);   // NT: write-once stream
}

// ---- fallback (ws too small): fp32 VALU, thread-per-edge, W1 in LDS ----
__global__ __launch_bounds__(256) void edge_mlp_fp32(
    const float* __restrict__ ue, const float* __restrict__ ie,
    const float* __restrict__ W1, const float* __restrict__ b1,
    const float* __restrict__ w2, const float* __restrict__ b2v,
    const int* __restrict__ idx, float* __restrict__ out, long E)
{
    __shared__ float w1s[128][32];
    for (int t = threadIdx.x; t < 4096; t += blockDim.x) {
        int k = t >> 5, j = t & 31;
        w1s[k][j] = W1[j * 128 + k];
    }
    __syncthreads();
    long e = (long)blockIdx.x * blockDim.x + threadIdx.x;
    if (e >= E) return;
    int u = idx[e], it = idx[E + e];
    const float* ur = ue + (long)u * 64;
    const float* ir = ie + (long)it * 64;
    float acc[32];
#pragma unroll
    for (int j = 0; j < 32; ++j) acc[j] = b1[j];
    for (int k = 0; k < 64; k += 4) {
        float4 f = *reinterpret_cast<const float4*>(ur + k);
        float fv[4] = {f.x, f.y, f.z, f.w};
#pragma unroll
        for (int q = 0; q < 4; ++q)
#pragma unroll
            for (int j = 0; j < 32; ++j) acc[j] += w1s[k + q][j] * fv[q];
    }
    for (int k = 0; k < 64; k += 4) {
        float4 f = *reinterpret_cast<const float4*>(ir + k);
        float fv[4] = {f.x, f.y, f.z, f.w};
#pragma unroll
        for (int q = 0; q < 4; ++q)
#pragma unroll
            for (int j = 0; j < 32; ++j) acc[j] += w1s[64 + k + q][j] * fv[q];
    }
    float lgt = b2v[0];
#pragma unroll
    for (int j = 0; j < 32; ++j) {
        float h = acc[j]; h = h >= 0.f ? h : 0.2f * h;
        lgt += h * w2[j];
    }
    out[e] = 1.0f / (1.0f + expf(-lgt));
}

extern "C" void kernel_launch(void* const* d_in, const int* in_sizes, int n_in,
                              void* d_out, int out_size, void* d_ws, size_t ws_size,
                              hipStream_t stream) {
    const float* ue  = (const float*)d_in[0];
    const float* ie  = (const float*)d_in[1];
    const float* W1  = (const float*)d_in[2];
    const float* b1  = (const float*)d_in[3];
    const float* w2  = (const float*)d_in[4];
    const float* b2v = (const float*)d_in[5];
    const int*   idx = (const int*)d_in[6];
    float* out = (float*)d_out;

    long nu = in_sizes[0] / 64;
    long ni = in_sizes[1] / 64;
    long E  = in_sizes[6] / 2;

    size_t need = (size_t)(nu + ni) * 32 * sizeof(_Float16);
    if (ws_size >= need) {
        _Float16* hu = (_Float16*)d_ws;
        _Float16* hi = hu + (size_t)nu * 32;

        int ntu = (int)((nu + 15) / 16);
        int nti = (int)((ni + 15) / 16);
        int ntot = ntu + nti;
        int pblocks = (ntot + 3) / 4;
        precompute_h<<<pblocks, 256, 0, stream>>>(ue, ie, W1, b1, hu, hi,
                                                  (int)nu, (int)ni, ntu, ntot);

        long ngroups = (E + 63) / 64;
        int mblocks = (int)((ngroups + 3) / 4);
        edge_final<<<mblocks, 256, 0, stream>>>(hu, hi, w2, b2v, idx, out, E, ngroups);
    } else {
        edge_mlp_fp32<<<(int)((E + 255) / 256), 256, 0, stream>>>(
            ue, ie, W1, b1, w2, b2v, idx, out, E);
    }
}